// Round 8
// baseline (1454.859 us; speedup 1.0000x reference)
//
#include <hip/hip_runtime.h>
#include <hip/hip_bf16.h>

#define EPSQ 1e-7f

#define BSZ 128
#define M2 4608           // B*36 conv2 output positions
#define K2 20736          // 81*256
#define KSTEPS 648        // K2/32

// ws offsets in floats (liveness-overlapped).
// Phase 1 (conv): c1 hi/lo [0, 13,107,200), w2t hi/lo [13,107,200, 18,415,616),
//                 CPART [18,415,616, +ksplit*1,179,648)
// Phase 2 (routing): PC/S1P/S2P/V1/H0/NRM reuse the dead-c1 region.
#define WS_C1H   0
#define WS_C1L   6553600
#define WS_W2TH  13107200
#define WS_W2TL  15761408
#define WS_CPART 18415616
#define WS_PC    0              // 1,179,648 fl
#define WS_S1P   1179648        // 144*20480 = 2,949,120 fl
#define WS_S2P   4128768        // 2,949,120 fl
#define WS_V1    7077888        // 20,480
#define WS_H0    7098368        // 20,480 (masked v2)
#define WS_NRM   7118848        // 1,280

typedef __attribute__((ext_vector_type(8))) short short8;
typedef __attribute__((ext_vector_type(4))) float floatx4;

#define DOT8(W0, W1, P) ((W0).x*(P)[0] + (W0).y*(P)[1] + (W0).z*(P)[2] + (W0).w*(P)[3] + \
                         (W1).x*(P)[4] + (W1).y*(P)[5] + (W1).z*(P)[6] + (W1).w*(P)[7])

__device__ inline ushort bf16_rne(float x) {
    union { float f; unsigned u; } v; v.f = x;
    unsigned r = v.u + 0x7FFFu + ((v.u >> 16) & 1u);
    return (ushort)(r >> 16);
}
__device__ inline float bf16_to_f(ushort h) {
    union { unsigned u; float f; } v; v.u = ((unsigned)h) << 16;
    return v.f;
}

// ---------------- fused conv1 (blocks [0,2560)) + w2 transpose ([2560,3856)) ----
__global__ __launch_bounds__(256) void convprep_kernel(const float* __restrict__ img,
        const float* __restrict__ w1, const float* __restrict__ b1,
        const float* __restrict__ w2,
        ushort* __restrict__ c1h, ushort* __restrict__ c1l,
        ushort* __restrict__ w2th, ushort* __restrict__ w2tl) {
    __shared__ float sm[4160];
    int t = threadIdx.x;
    int bid = blockIdx.x;
    if (bid < 2560) {
        int b = bid / 20, oh = bid % 20;
        if (t < 252) sm[t] = img[b * 784 + oh * 28 + t];
        __syncthreads();
        float acc[20];
#pragma unroll
        for (int ow = 0; ow < 20; ++ow) acc[ow] = 0.f;
        for (int kh = 0; kh < 9; ++kh) {
            float row[28];
#pragma unroll
            for (int c = 0; c < 28; ++c) row[c] = sm[kh * 28 + c];
#pragma unroll
            for (int kw = 0; kw < 9; ++kw) {
                float wv = w1[(kh * 9 + kw) * 256 + t];
#pragma unroll
                for (int ow = 0; ow < 20; ++ow) acc[ow] += row[kw + ow] * wv;
            }
        }
        float bias = b1[t];
        size_t opos = ((size_t)(b * 20 + oh) * 20) * 256 + t;
#pragma unroll
        for (int ow = 0; ow < 20; ++ow) {
            float x = fmaxf(acc[ow] + bias, 0.f);
            ushort h = bf16_rne(x);
            c1h[opos + (size_t)ow * 256] = h;
            c1l[opos + (size_t)ow * 256] = bf16_rne(x - bf16_to_f(h));
        }
    } else {
        int pb = bid - 2560;                 // 1296 = 324 kt x 4 nt
        int kt = pb >> 2, nt = pb & 3;
        int tn = t & 63, t4 = t >> 6;
#pragma unroll
        for (int i = 0; i < 16; ++i) {
            int k = i * 4 + t4;
            sm[k * 65 + tn] = w2[(size_t)(kt * 64 + k) * 256 + nt * 64 + tn];
        }
        __syncthreads();
        int tk = t & 63;
#pragma unroll
        for (int i = 0; i < 16; ++i) {
            int n = i * 4 + t4;
            float x = sm[tk * 65 + n];
            ushort h = bf16_rne(x);
            ushort lo = bf16_rne(x - bf16_to_f(h));
            size_t o = (size_t)(nt * 64 + n) * 20736 + kt * 64 + tk;
            w2th[o] = h; w2tl[o] = lo;
        }
    }
}

// -------- conv2 MFMA GEMM (R6-verified: 168 us, conflicts 0) --------------------
#define LDS_AH 0
#define LDS_AL 4096
#define LDS_BH 8192
#define LDS_BL 16384
__global__ __launch_bounds__(256) void conv2_mfma_kernel(
        const ushort* __restrict__ c1h, const ushort* __restrict__ c1l,
        const ushort* __restrict__ w2th, const ushort* __restrict__ w2tl,
        float* __restrict__ part, int nsteps, int nwg) {
    int bid = blockIdx.x;
    int v = (bid & 7) * (nwg >> 3) + (bid >> 3);   // bijective: 8 | nwg
    int mt = v % 72, grp = v / 72;
    int nt = grp & 1, ks = grp >> 1;
    int t = threadIdx.x;
    int m0 = mt * 64, n0 = nt * 128;
    __shared__ __attribute__((aligned(16))) ushort lds[24576];   // 48 KB

    int sr = t >> 3, sc = t & 7;
    int mA0 = m0 + sr, mA1 = m0 + sr + 32;
    int b0_ = mA0 / 36, r0_ = mA0 % 36;
    int b1_ = mA1 / 36, r1_ = mA1 % 36;
    int pb0 = ((b0_ * 20 + (r0_ / 6) * 2) * 20 + (r0_ % 6) * 2) * 256;
    int pb1 = ((b1_ * 20 + (r1_ / 6) * 2) * 20 + (r1_ % 6) * 2) * 256;
    size_t wb = (size_t)(n0 + sr) * 20736 + sc * 8;
    int wOff = sr * 64 + ((sc ^ (sr & 7)) * 8);

    int lane = t & 63, wave = t >> 6;
    int l15 = lane & 15, g = lane >> 4;
    int wrb = (wave >> 1) * 32, wcb = (wave & 1) * 64;

    floatx4 acc[2][4];
#pragma unroll
    for (int mi = 0; mi < 2; ++mi)
#pragma unroll
        for (int nj = 0; nj < 4; ++nj) acc[mi][nj] = (floatx4)0.f;

    int st0 = ks * nsteps;
    uint4 A0h, A1h, A0l, A1l, B0h, B1h, B2h, B3h, B0l, B1l, B2l, B3l;
#define LOADG64(ST) { \
        int kb = (ST) * 64; \
        int khkw = kb >> 8; int kh = khkw / 9, kw = khkw - kh * 9; \
        int ao = (kh * 20 + kw) * 256 + (kb & 255) + sc * 8; \
        A0h = *(const uint4*)(c1h + pb0 + ao); \
        A1h = *(const uint4*)(c1h + pb1 + ao); \
        A0l = *(const uint4*)(c1l + pb0 + ao); \
        A1l = *(const uint4*)(c1l + pb1 + ao); \
        size_t bo = wb + kb; \
        B0h = *(const uint4*)(w2th + bo); \
        B1h = *(const uint4*)(w2th + bo + (size_t)32 * 20736); \
        B2h = *(const uint4*)(w2th + bo + (size_t)64 * 20736); \
        B3h = *(const uint4*)(w2th + bo + (size_t)96 * 20736); \
        B0l = *(const uint4*)(w2tl + bo); \
        B1l = *(const uint4*)(w2tl + bo + (size_t)32 * 20736); \
        B2l = *(const uint4*)(w2tl + bo + (size_t)64 * 20736); \
        B3l = *(const uint4*)(w2tl + bo + (size_t)96 * 20736); }

    LOADG64(st0);
    for (int st = 0; st < nsteps; ++st) {
        __syncthreads();
        *(uint4*)&lds[LDS_AH + wOff]        = A0h;
        *(uint4*)&lds[LDS_AH + wOff + 2048] = A1h;
        *(uint4*)&lds[LDS_AL + wOff]        = A0l;
        *(uint4*)&lds[LDS_AL + wOff + 2048] = A1l;
        *(uint4*)&lds[LDS_BH + wOff]        = B0h;
        *(uint4*)&lds[LDS_BH + wOff + 2048] = B1h;
        *(uint4*)&lds[LDS_BH + wOff + 4096] = B2h;
        *(uint4*)&lds[LDS_BH + wOff + 6144] = B3h;
        *(uint4*)&lds[LDS_BL + wOff]        = B0l;
        *(uint4*)&lds[LDS_BL + wOff + 2048] = B1l;
        *(uint4*)&lds[LDS_BL + wOff + 4096] = B2l;
        *(uint4*)&lds[LDS_BL + wOff + 6144] = B3l;
        __syncthreads();
        if (st + 1 < nsteps) LOADG64(st0 + st + 1);

#pragma unroll
        for (int kk = 0; kk < 2; ++kk) {
            int sl = kk * 4 + g;
            short8 ah[2], al[2], bh[4], bl[4];
#pragma unroll
            for (int mi = 0; mi < 2; ++mi) {
                int r = wrb + mi * 16 + l15;
                int ro = r * 64 + ((sl ^ (r & 7)) * 8);
                ah[mi] = *(const short8*)&lds[LDS_AH + ro];
                al[mi] = *(const short8*)&lds[LDS_AL + ro];
            }
#pragma unroll
            for (int nj = 0; nj < 4; ++nj) {
                int c = wcb + nj * 16 + l15;
                int co = c * 64 + ((sl ^ (c & 7)) * 8);
                bh[nj] = *(const short8*)&lds[LDS_BH + co];
                bl[nj] = *(const short8*)&lds[LDS_BL + co];
            }
#pragma unroll
            for (int mi = 0; mi < 2; ++mi)
#pragma unroll
                for (int nj = 0; nj < 4; ++nj) {
                    acc[mi][nj] = __builtin_amdgcn_mfma_f32_16x16x32_bf16(ah[mi], bh[nj], acc[mi][nj], 0, 0, 0);
                    acc[mi][nj] = __builtin_amdgcn_mfma_f32_16x16x32_bf16(ah[mi], bl[nj], acc[mi][nj], 0, 0, 0);
                    acc[mi][nj] = __builtin_amdgcn_mfma_f32_16x16x32_bf16(al[mi], bh[nj], acc[mi][nj], 0, 0, 0);
                }
        }
    }
    size_t obase = (size_t)ks * M2 * 256;
#pragma unroll
    for (int mi = 0; mi < 2; ++mi)
#pragma unroll
        for (int nj = 0; nj < 4; ++nj) {
            int col = n0 + wcb + nj * 16 + l15;
            int rowb = m0 + wrb + mi * 16 + (lane >> 4) * 4;
#pragma unroll
            for (int r = 0; r < 4; ++r)
                part[obase + (size_t)(rowb + r) * 256 + col] = acc[mi][nj][r];
        }
}

// -------- reduce k-split partials + bias + relu + squash(8) -> pc ---------------
__global__ __launch_bounds__(256) void squash_pc_kernel(const float* __restrict__ part,
        const float* __restrict__ b2, float* __restrict__ pc, int nsplit) {
    int m = blockIdx.x;
    int n = threadIdx.x;
    size_t idx = (size_t)m * 256 + n;
    const size_t stride = (size_t)M2 * 256;
    float v = 0.f;
    for (int s = 0; s < nsplit; ++s) v += part[idx + s * stride];
    v = fmaxf(v + b2[n], 0.f);
    float sq = v * v;
    sq += __shfl_xor(sq, 1, 8);
    sq += __shfl_xor(sq, 2, 8);
    sq += __shfl_xor(sq, 4, 8);
    float scale = sq / ((1.f + sq) * sqrtf(sq + EPSQ));
    pc[idx] = v * scale;
}

// -------- s1 partials: grid (144 i-chunks x 8 b-groups), W in regs --------------
__global__ __launch_bounds__(192) void s1part_kernel(const float* __restrict__ Wm,
        const float* __restrict__ pc, float* __restrict__ s1p) {
    int ic = blockIdx.x, bg = blockIdx.y;
    int i0 = ic * 8, b0 = bg * 16;
    int t = threadIdx.x;
    __shared__ float pcl[16][68];
    for (int e = t; e < 1024; e += 192) {
        int bl = e >> 6, off = e & 63;
        pcl[bl][off] = pc[(size_t)(b0 + bl) * 9216 + i0 * 8 + off];
    }
    __syncthreads();
    if (t >= 160) return;
    float4 w[8][2];
#pragma unroll
    for (int ii = 0; ii < 8; ++ii) {
        const float4* wp = (const float4*)&Wm[(size_t)(i0 + ii) * 1280 + t * 8];
        w[ii][0] = wp[0]; w[ii][1] = wp[1];
    }
    for (int bl = 0; bl < 16; ++bl) {
        float s = 0.f;
#pragma unroll
        for (int ii = 0; ii < 8; ++ii) {
            const float* p = &pcl[bl][ii * 8];
            s += DOT8(w[ii][0], w[ii][1], p);
        }
        s1p[(size_t)ic * 20480 + (b0 + bl) * 160 + t] = s;
    }
}

// -------- v1 = squash_d(0.1 * sum over 144), coalesced thread-per-output --------
__global__ __launch_bounds__(256) void v1red_kernel(const float* __restrict__ s1p,
        float* __restrict__ v1) {
    int gid = blockIdx.x * 256 + threadIdx.x;    // 0..20479
    float s = 0.f;
    for (int kc = 0; kc < 144; ++kc) s += s1p[(size_t)kc * 20480 + gid];
    s *= 0.1f;
    float sq = s * s;
    sq += __shfl_xor(sq, 1, 16);
    sq += __shfl_xor(sq, 2, 16);
    sq += __shfl_xor(sq, 4, 16);
    sq += __shfl_xor(sq, 8, 16);
    v1[gid] = s * sq / ((1.f + sq) * sqrtf(sq + EPSQ));
}

// -------- c2 (agreement+softmax) + s2 partials; grid (144 x 8) ------------------
__global__ __launch_bounds__(192) void c2s2_kernel(const float* __restrict__ Wm,
        const float* __restrict__ pc, const float* __restrict__ v1,
        float* __restrict__ s2p) {
    int ic = blockIdx.x, bg = blockIdx.y;
    int i0 = ic * 8, b0 = bg * 16;
    int t = threadIdx.x;
    __shared__ float pcl[16][68];
    __shared__ float uvl[8][16][10];
    for (int e = t; e < 1024; e += 192) {
        int bl = e >> 6, off = e & 63;
        pcl[bl][off] = pc[(size_t)(b0 + bl) * 9216 + i0 * 8 + off];
    }
    __syncthreads();
    int j = t >> 4;
    float4 w[8][2];
    if (t < 160) {
#pragma unroll
        for (int ii = 0; ii < 8; ++ii) {
            const float4* wp = (const float4*)&Wm[(size_t)(i0 + ii) * 1280 + t * 8];
            w[ii][0] = wp[0]; w[ii][1] = wp[1];
        }
        for (int bl = 0; bl < 16; ++bl) {
            float vv = v1[(b0 + bl) * 160 + t];
#pragma unroll
            for (int ii = 0; ii < 8; ++ii) {
                const float* p = &pcl[bl][ii * 8];
                float u = DOT8(w[ii][0], w[ii][1], p);
                float pr = u * vv;
                pr += __shfl_xor(pr, 1, 16);
                pr += __shfl_xor(pr, 2, 16);
                pr += __shfl_xor(pr, 4, 16);
                pr += __shfl_xor(pr, 8, 16);
                if ((t & 15) == 0) uvl[ii][bl][j] = pr;
            }
        }
    }
    __syncthreads();
    if (t < 128) {
        int ii = t >> 4, bl = t & 15;
        float* uv = uvl[ii][bl];
        float mx = uv[0];
#pragma unroll
        for (int jj = 1; jj < 10; ++jj) mx = fmaxf(mx, uv[jj]);
        float sum = 0.f;
        float ex[10];
#pragma unroll
        for (int jj = 0; jj < 10; ++jj) { ex[jj] = expf(uv[jj] - mx); sum += ex[jj]; }
        float inv = 1.f / sum;
#pragma unroll
        for (int jj = 0; jj < 10; ++jj) uv[jj] = ex[jj] * inv;
    }
    __syncthreads();
    if (t >= 160) return;
    for (int bl = 0; bl < 16; ++bl) {
        float acc = 0.f;
#pragma unroll
        for (int ii = 0; ii < 8; ++ii) {
            const float* p = &pcl[bl][ii * 8];
            float u = DOT8(w[ii][0], w[ii][1], p);
            acc += uvl[ii][bl][j] * u;
        }
        s2p[(size_t)ic * 20480 + (b0 + bl) * 160 + t] = acc;
    }
}

// -------- v2 + norm + mask, coalesced thread-per-output -------------------------
__global__ __launch_bounds__(256) void v2red_kernel(const float* __restrict__ s2p,
        const int* __restrict__ target, float* __restrict__ h0,
        float* __restrict__ nrm, float* __restrict__ out) {
    int gid = blockIdx.x * 256 + threadIdx.x;    // 0..20479
    int d = gid & 15, bj = gid >> 4;
    int j = bj % 10, b = bj / 10;
    float s = 0.f;
    for (int kc = 0; kc < 144; ++kc) s += s2p[(size_t)kc * 20480 + gid];
    float sq = s * s;
    sq += __shfl_xor(sq, 1, 16);
    sq += __shfl_xor(sq, 2, 16);
    sq += __shfl_xor(sq, 4, 16);
    sq += __shfl_xor(sq, 8, 16);
    float v = s * sq / ((1.f + sq) * sqrtf(sq + EPSQ));
    float vsq = v * v;
    vsq += __shfl_xor(vsq, 1, 16);
    vsq += __shfl_xor(vsq, 2, 16);
    vsq += __shfl_xor(vsq, 4, 16);
    vsq += __shfl_xor(vsq, 8, 16);
    float norm = sqrtf(vsq + EPSQ);
    h0[gid] = (j == target[b]) ? v : 0.f;
    if (d == 0) { nrm[b * 10 + j] = norm; out[b * 10 + j] = norm; }
}

// -------- fused decoder: argmax + fc1 + fc2 + fc3 (2 batches/block in LDS) ------
__global__ __launch_bounds__(256) void decoder_kernel(const float* __restrict__ h0,
        const float* __restrict__ nrm, const float* __restrict__ d1w,
        const float* __restrict__ d1b, const float* __restrict__ d2w,
        const float* __restrict__ d2b, const float* __restrict__ dow,
        const float* __restrict__ dob, float* __restrict__ out) {
    int b0 = blockIdx.x * 2;
    int t = threadIdx.x;
    __shared__ float h0s[2][160];
    __shared__ float h1s[2][512];
    __shared__ float h2s[2][1024];
    for (int e = t; e < 320; e += 256) {
        int bb = e >= 160, idx = e - bb * 160;
        h0s[bb][idx] = h0[(size_t)(b0 + bb) * 160 + idx];
    }
    if (t < 2) {
        int b = b0 + t;
        float best = nrm[b * 10]; int am = 0;
#pragma unroll
        for (int jj = 1; jj < 10; ++jj) {
            float n2 = nrm[b * 10 + jj];
            if (n2 > best) { best = n2; am = jj; }
        }
        out[1280 + b] = (float)am;
    }
    __syncthreads();
    // fc1: 512 outputs, n = t, t+256
    {
        float a00 = d1b[t], a01 = d1b[t + 256];
        float a10 = a00, a11 = a01;
        for (int k = 0; k < 160; ++k) {
            float w0 = d1w[k * 512 + t];
            float w1 = d1w[k * 512 + t + 256];
            float x0 = h0s[0][k], x1 = h0s[1][k];
            a00 += x0 * w0; a01 += x0 * w1;
            a10 += x1 * w0; a11 += x1 * w1;
        }
        h1s[0][t] = fmaxf(a00, 0.f); h1s[0][t + 256] = fmaxf(a01, 0.f);
        h1s[1][t] = fmaxf(a10, 0.f); h1s[1][t + 256] = fmaxf(a11, 0.f);
    }
    __syncthreads();
    // fc2: 1024 outputs, n = t + 256*r
    {
        float a0[2][4];
#pragma unroll
        for (int r = 0; r < 4; ++r) { a0[0][r] = d2b[t + 256 * r]; a0[1][r] = a0[0][r]; }
        for (int k = 0; k < 512; ++k) {
            float x0 = h1s[0][k], x1 = h1s[1][k];
#pragma unroll
            for (int r = 0; r < 4; ++r) {
                float wv = d2w[(size_t)k * 1024 + t + 256 * r];
                a0[0][r] += x0 * wv; a0[1][r] += x1 * wv;
            }
        }
#pragma unroll
        for (int r = 0; r < 4; ++r) {
            h2s[0][t + 256 * r] = fmaxf(a0[0][r], 0.f);
            h2s[1][t + 256 * r] = fmaxf(a0[1][r], 0.f);
        }
    }
    __syncthreads();
    // fc3: 784 outputs (sigmoid), n = t + 256*r (valid while < 784)
    {
        float a0[2][4];
#pragma unroll
        for (int r = 0; r < 4; ++r) {
            int n = t + 256 * r;
            float bv = (n < 784) ? dob[n] : 0.f;
            a0[0][r] = bv; a0[1][r] = bv;
        }
        for (int k = 0; k < 1024; ++k) {
            float x0 = h2s[0][k], x1 = h2s[1][k];
#pragma unroll
            for (int r = 0; r < 4; ++r) {
                int n = t + 256 * r;
                if (n < 784) {
                    float wv = dow[(size_t)k * 784 + n];
                    a0[0][r] += x0 * wv; a0[1][r] += x1 * wv;
                }
            }
        }
#pragma unroll
        for (int r = 0; r < 4; ++r) {
            int n = t + 256 * r;
            if (n < 784) {
                out[1408 + (size_t)b0 * 784 + n] = 1.f / (1.f + expf(-a0[0][r]));
                out[1408 + (size_t)(b0 + 1) * 784 + n] = 1.f / (1.f + expf(-a0[1][r]));
            }
        }
    }
}

extern "C" void kernel_launch(void* const* d_in, const int* in_sizes, int n_in,
                              void* d_out, int out_size, void* d_ws, size_t ws_size,
                              hipStream_t stream) {
    const float* image = (const float*)d_in[0];
    const int*   target = (const int*)d_in[1];
    const float* w1  = (const float*)d_in[2];
    const float* b1  = (const float*)d_in[3];
    const float* w2  = (const float*)d_in[4];
    const float* b2  = (const float*)d_in[5];
    const float* Wm  = (const float*)d_in[6];
    const float* d1w = (const float*)d_in[7];
    const float* d1b = (const float*)d_in[8];
    const float* d2w = (const float*)d_in[9];
    const float* d2b = (const float*)d_in[10];
    const float* dow = (const float*)d_in[11];
    const float* dob = (const float*)d_in[12];
    float* out = (float*)d_out;
    float* ws  = (float*)d_ws;

    ushort* c1h  = (ushort*)(ws + WS_C1H);
    ushort* c1l  = (ushort*)(ws + WS_C1L);
    ushort* w2th = (ushort*)(ws + WS_W2TH);
    ushort* w2tl = (ushort*)(ws + WS_W2TL);

    int ksplit = 4;
    if (ws_size >= (size_t)(18415616 + 18 * 1179648) * 4) ksplit = 18;
    else if (ws_size >= (size_t)(18415616 + 12 * 1179648) * 4) ksplit = 12;
    else if (ws_size >= (size_t)(18415616 + 6 * 1179648) * 4) ksplit = 6;
    int nsteps = KSTEPS / ksplit / 2;
    int nwg = 144 * ksplit;

    convprep_kernel<<<3856, 256, 0, stream>>>(image, w1, b1, w2, c1h, c1l, w2th, w2tl);
    conv2_mfma_kernel<<<nwg, 256, 0, stream>>>(c1h, c1l, w2th, w2tl,
                                               ws + WS_CPART, nsteps, nwg);
    squash_pc_kernel<<<4608, 256, 0, stream>>>(ws + WS_CPART, b2, ws + WS_PC, ksplit);
    s1part_kernel<<<dim3(144, 8), 192, 0, stream>>>(Wm, ws + WS_PC, ws + WS_S1P);
    v1red_kernel<<<80, 256, 0, stream>>>(ws + WS_S1P, ws + WS_V1);
    c2s2_kernel<<<dim3(144, 8), 192, 0, stream>>>(Wm, ws + WS_PC, ws + WS_V1, ws + WS_S2P);
    v2red_kernel<<<80, 256, 0, stream>>>(ws + WS_S2P, target, ws + WS_H0,
                                         ws + WS_NRM, out);
    decoder_kernel<<<64, 256, 0, stream>>>(ws + WS_H0, ws + WS_NRM,
                                           d1w, d1b, d2w, d2b, dow, dob, out);
}

// Round 9
// 501.796 us; speedup vs baseline: 2.8993x; 2.8993x over previous
//
#include <hip/hip_runtime.h>
#include <hip/hip_bf16.h>

#define EPSQ 1e-7f

#define BSZ 128
#define M2 4608           // B*36 conv2 output positions
#define K2 20736          // 81*256
#define KSTEPS 648        // K2/32

// ws offsets in floats (liveness-overlapped).
// Phase 1 (conv): c1 hi/lo [0, 13,107,200), w2t hi/lo [13,107,200, 18,415,616),
//                 CPART [18,415,616, +ksplit*1,179,648)
// Phase 2 (routing): PC/S1P/S2P/V1/H0/NRM reuse dead-c1; H1/H2 reuse dead-w2t.
#define WS_C1H   0
#define WS_C1L   6553600
#define WS_W2TH  13107200
#define WS_W2TL  15761408
#define WS_CPART 18415616
#define WS_PC    0              // 1,179,648 fl
#define WS_S1P   1179648        // 144*20480 = 2,949,120 fl
#define WS_S2P   4128768        // 2,949,120 fl
#define WS_V1    7077888        // 20,480
#define WS_H0    7098368        // 20,480 (masked v2)
#define WS_NRM   7118848        // 1,280
#define WS_H1    13107200       // 65,536 (w2t dead)
#define WS_H2    13172736       // 131,072

typedef __attribute__((ext_vector_type(8))) short short8;
typedef __attribute__((ext_vector_type(4))) float floatx4;

#define DOT8(W0, W1, P) ((W0).x*(P)[0] + (W0).y*(P)[1] + (W0).z*(P)[2] + (W0).w*(P)[3] + \
                         (W1).x*(P)[4] + (W1).y*(P)[5] + (W1).z*(P)[6] + (W1).w*(P)[7])

__device__ inline ushort bf16_rne(float x) {
    union { float f; unsigned u; } v; v.f = x;
    unsigned r = v.u + 0x7FFFu + ((v.u >> 16) & 1u);
    return (ushort)(r >> 16);
}
__device__ inline float bf16_to_f(ushort h) {
    union { unsigned u; float f; } v; v.u = ((unsigned)h) << 16;
    return v.f;
}

// ---------------- fused conv1 (blocks [0,2560)) + w2 transpose ([2560,3856)) ----
__global__ __launch_bounds__(256) void convprep_kernel(const float* __restrict__ img,
        const float* __restrict__ w1, const float* __restrict__ b1,
        const float* __restrict__ w2,
        ushort* __restrict__ c1h, ushort* __restrict__ c1l,
        ushort* __restrict__ w2th, ushort* __restrict__ w2tl) {
    __shared__ float sm[4160];
    int t = threadIdx.x;
    int bid = blockIdx.x;
    if (bid < 2560) {
        int b = bid / 20, oh = bid % 20;
        if (t < 252) sm[t] = img[b * 784 + oh * 28 + t];
        __syncthreads();
        float acc[20];
#pragma unroll
        for (int ow = 0; ow < 20; ++ow) acc[ow] = 0.f;
        for (int kh = 0; kh < 9; ++kh) {
            float row[28];
#pragma unroll
            for (int c = 0; c < 28; ++c) row[c] = sm[kh * 28 + c];
#pragma unroll
            for (int kw = 0; kw < 9; ++kw) {
                float wv = w1[(kh * 9 + kw) * 256 + t];
#pragma unroll
                for (int ow = 0; ow < 20; ++ow) acc[ow] += row[kw + ow] * wv;
            }
        }
        float bias = b1[t];
        size_t opos = ((size_t)(b * 20 + oh) * 20) * 256 + t;
#pragma unroll
        for (int ow = 0; ow < 20; ++ow) {
            float x = fmaxf(acc[ow] + bias, 0.f);
            ushort h = bf16_rne(x);
            c1h[opos + (size_t)ow * 256] = h;
            c1l[opos + (size_t)ow * 256] = bf16_rne(x - bf16_to_f(h));
        }
    } else {
        int pb = bid - 2560;                 // 1296 = 324 kt x 4 nt
        int kt = pb >> 2, nt = pb & 3;
        int tn = t & 63, t4 = t >> 6;
#pragma unroll
        for (int i = 0; i < 16; ++i) {
            int k = i * 4 + t4;
            sm[k * 65 + tn] = w2[(size_t)(kt * 64 + k) * 256 + nt * 64 + tn];
        }
        __syncthreads();
        int tk = t & 63;
#pragma unroll
        for (int i = 0; i < 16; ++i) {
            int n = i * 4 + t4;
            float x = sm[tk * 65 + n];
            ushort h = bf16_rne(x);
            ushort lo = bf16_rne(x - bf16_to_f(h));
            size_t o = (size_t)(nt * 64 + n) * 20736 + kt * 64 + tk;
            w2th[o] = h; w2tl[o] = lo;
        }
    }
}

// -------- conv2 MFMA GEMM (R6-verified: 168 us, conflicts 0) --------------------
#define LDS_AH 0
#define LDS_AL 4096
#define LDS_BH 8192
#define LDS_BL 16384
__global__ __launch_bounds__(256) void conv2_mfma_kernel(
        const ushort* __restrict__ c1h, const ushort* __restrict__ c1l,
        const ushort* __restrict__ w2th, const ushort* __restrict__ w2tl,
        float* __restrict__ part, int nsteps, int nwg) {
    int bid = blockIdx.x;
    int v = (bid & 7) * (nwg >> 3) + (bid >> 3);   // bijective: 8 | nwg
    int mt = v % 72, grp = v / 72;
    int nt = grp & 1, ks = grp >> 1;
    int t = threadIdx.x;
    int m0 = mt * 64, n0 = nt * 128;
    __shared__ __attribute__((aligned(16))) ushort lds[24576];   // 48 KB

    int sr = t >> 3, sc = t & 7;
    int mA0 = m0 + sr, mA1 = m0 + sr + 32;
    int b0_ = mA0 / 36, r0_ = mA0 % 36;
    int b1_ = mA1 / 36, r1_ = mA1 % 36;
    int pb0 = ((b0_ * 20 + (r0_ / 6) * 2) * 20 + (r0_ % 6) * 2) * 256;
    int pb1 = ((b1_ * 20 + (r1_ / 6) * 2) * 20 + (r1_ % 6) * 2) * 256;
    size_t wb = (size_t)(n0 + sr) * 20736 + sc * 8;
    int wOff = sr * 64 + ((sc ^ (sr & 7)) * 8);

    int lane = t & 63, wave = t >> 6;
    int l15 = lane & 15, g = lane >> 4;
    int wrb = (wave >> 1) * 32, wcb = (wave & 1) * 64;

    floatx4 acc[2][4];
#pragma unroll
    for (int mi = 0; mi < 2; ++mi)
#pragma unroll
        for (int nj = 0; nj < 4; ++nj) acc[mi][nj] = (floatx4)0.f;

    int st0 = ks * nsteps;
    uint4 A0h, A1h, A0l, A1l, B0h, B1h, B2h, B3h, B0l, B1l, B2l, B3l;
#define LOADG64(ST) { \
        int kb = (ST) * 64; \
        int khkw = kb >> 8; int kh = khkw / 9, kw = khkw - kh * 9; \
        int ao = (kh * 20 + kw) * 256 + (kb & 255) + sc * 8; \
        A0h = *(const uint4*)(c1h + pb0 + ao); \
        A1h = *(const uint4*)(c1h + pb1 + ao); \
        A0l = *(const uint4*)(c1l + pb0 + ao); \
        A1l = *(const uint4*)(c1l + pb1 + ao); \
        size_t bo = wb + kb; \
        B0h = *(const uint4*)(w2th + bo); \
        B1h = *(const uint4*)(w2th + bo + (size_t)32 * 20736); \
        B2h = *(const uint4*)(w2th + bo + (size_t)64 * 20736); \
        B3h = *(const uint4*)(w2th + bo + (size_t)96 * 20736); \
        B0l = *(const uint4*)(w2tl + bo); \
        B1l = *(const uint4*)(w2tl + bo + (size_t)32 * 20736); \
        B2l = *(const uint4*)(w2tl + bo + (size_t)64 * 20736); \
        B3l = *(const uint4*)(w2tl + bo + (size_t)96 * 20736); }

    LOADG64(st0);
    for (int st = 0; st < nsteps; ++st) {
        __syncthreads();
        *(uint4*)&lds[LDS_AH + wOff]        = A0h;
        *(uint4*)&lds[LDS_AH + wOff + 2048] = A1h;
        *(uint4*)&lds[LDS_AL + wOff]        = A0l;
        *(uint4*)&lds[LDS_AL + wOff + 2048] = A1l;
        *(uint4*)&lds[LDS_BH + wOff]        = B0h;
        *(uint4*)&lds[LDS_BH + wOff + 2048] = B1h;
        *(uint4*)&lds[LDS_BH + wOff + 4096] = B2h;
        *(uint4*)&lds[LDS_BH + wOff + 6144] = B3h;
        *(uint4*)&lds[LDS_BL + wOff]        = B0l;
        *(uint4*)&lds[LDS_BL + wOff + 2048] = B1l;
        *(uint4*)&lds[LDS_BL + wOff + 4096] = B2l;
        *(uint4*)&lds[LDS_BL + wOff + 6144] = B3l;
        __syncthreads();
        if (st + 1 < nsteps) LOADG64(st0 + st + 1);

#pragma unroll
        for (int kk = 0; kk < 2; ++kk) {
            int sl = kk * 4 + g;
            short8 ah[2], al[2], bh[4], bl[4];
#pragma unroll
            for (int mi = 0; mi < 2; ++mi) {
                int r = wrb + mi * 16 + l15;
                int ro = r * 64 + ((sl ^ (r & 7)) * 8);
                ah[mi] = *(const short8*)&lds[LDS_AH + ro];
                al[mi] = *(const short8*)&lds[LDS_AL + ro];
            }
#pragma unroll
            for (int nj = 0; nj < 4; ++nj) {
                int c = wcb + nj * 16 + l15;
                int co = c * 64 + ((sl ^ (c & 7)) * 8);
                bh[nj] = *(const short8*)&lds[LDS_BH + co];
                bl[nj] = *(const short8*)&lds[LDS_BL + co];
            }
#pragma unroll
            for (int mi = 0; mi < 2; ++mi)
#pragma unroll
                for (int nj = 0; nj < 4; ++nj) {
                    acc[mi][nj] = __builtin_amdgcn_mfma_f32_16x16x32_bf16(ah[mi], bh[nj], acc[mi][nj], 0, 0, 0);
                    acc[mi][nj] = __builtin_amdgcn_mfma_f32_16x16x32_bf16(ah[mi], bl[nj], acc[mi][nj], 0, 0, 0);
                    acc[mi][nj] = __builtin_amdgcn_mfma_f32_16x16x32_bf16(al[mi], bh[nj], acc[mi][nj], 0, 0, 0);
                }
        }
    }
    size_t obase = (size_t)ks * M2 * 256;
#pragma unroll
    for (int mi = 0; mi < 2; ++mi)
#pragma unroll
        for (int nj = 0; nj < 4; ++nj) {
            int col = n0 + wcb + nj * 16 + l15;
            int rowb = m0 + wrb + mi * 16 + (lane >> 4) * 4;
#pragma unroll
            for (int r = 0; r < 4; ++r)
                part[obase + (size_t)(rowb + r) * 256 + col] = acc[mi][nj][r];
        }
}

// -------- reduce k-split partials + bias + relu + squash(8) -> pc ---------------
__global__ __launch_bounds__(256) void squash_pc_kernel(const float* __restrict__ part,
        const float* __restrict__ b2, float* __restrict__ pc, int nsplit) {
    int m = blockIdx.x;
    int n = threadIdx.x;
    size_t idx = (size_t)m * 256 + n;
    const size_t stride = (size_t)M2 * 256;
    float v = 0.f;
    for (int s = 0; s < nsplit; ++s) v += part[idx + s * stride];
    v = fmaxf(v + b2[n], 0.f);
    float sq = v * v;
    sq += __shfl_xor(sq, 1, 8);
    sq += __shfl_xor(sq, 2, 8);
    sq += __shfl_xor(sq, 4, 8);
    float scale = sq / ((1.f + sq) * sqrtf(sq + EPSQ));
    pc[idx] = v * scale;
}

// -------- s1 partials: grid (144 i-chunks x 8 b-groups), W in regs --------------
__global__ __launch_bounds__(192) void s1part_kernel(const float* __restrict__ Wm,
        const float* __restrict__ pc, float* __restrict__ s1p) {
    int ic = blockIdx.x, bg = blockIdx.y;
    int i0 = ic * 8, b0 = bg * 16;
    int t = threadIdx.x;
    __shared__ float pcl[16][68];
    for (int e = t; e < 1024; e += 192) {
        int bl = e >> 6, off = e & 63;
        pcl[bl][off] = pc[(size_t)(b0 + bl) * 9216 + i0 * 8 + off];
    }
    __syncthreads();
    if (t >= 160) return;
    float4 w[8][2];
#pragma unroll
    for (int ii = 0; ii < 8; ++ii) {
        const float4* wp = (const float4*)&Wm[(size_t)(i0 + ii) * 1280 + t * 8];
        w[ii][0] = wp[0]; w[ii][1] = wp[1];
    }
    for (int bl = 0; bl < 16; ++bl) {
        float s = 0.f;
#pragma unroll
        for (int ii = 0; ii < 8; ++ii) {
            const float* p = &pcl[bl][ii * 8];
            s += DOT8(w[ii][0], w[ii][1], p);
        }
        s1p[(size_t)ic * 20480 + (b0 + bl) * 160 + t] = s;
    }
}

// -------- v1 = squash_d(0.1 * sum over 144), coalesced thread-per-output --------
__global__ __launch_bounds__(256) void v1red_kernel(const float* __restrict__ s1p,
        float* __restrict__ v1) {
    int gid = blockIdx.x * 256 + threadIdx.x;    // 0..20479
    float s = 0.f;
    for (int kc = 0; kc < 144; ++kc) s += s1p[(size_t)kc * 20480 + gid];
    s *= 0.1f;
    float sq = s * s;
    sq += __shfl_xor(sq, 1, 16);
    sq += __shfl_xor(sq, 2, 16);
    sq += __shfl_xor(sq, 4, 16);
    sq += __shfl_xor(sq, 8, 16);
    v1[gid] = s * sq / ((1.f + sq) * sqrtf(sq + EPSQ));
}

// -------- c2 (agreement+softmax) + s2 partials; grid (144 x 8) ------------------
__global__ __launch_bounds__(192) void c2s2_kernel(const float* __restrict__ Wm,
        const float* __restrict__ pc, const float* __restrict__ v1,
        float* __restrict__ s2p) {
    int ic = blockIdx.x, bg = blockIdx.y;
    int i0 = ic * 8, b0 = bg * 16;
    int t = threadIdx.x;
    __shared__ float pcl[16][68];
    __shared__ float uvl[8][16][10];
    for (int e = t; e < 1024; e += 192) {
        int bl = e >> 6, off = e & 63;
        pcl[bl][off] = pc[(size_t)(b0 + bl) * 9216 + i0 * 8 + off];
    }
    __syncthreads();
    int j = t >> 4;
    float4 w[8][2];
    if (t < 160) {
#pragma unroll
        for (int ii = 0; ii < 8; ++ii) {
            const float4* wp = (const float4*)&Wm[(size_t)(i0 + ii) * 1280 + t * 8];
            w[ii][0] = wp[0]; w[ii][1] = wp[1];
        }
        for (int bl = 0; bl < 16; ++bl) {
            float vv = v1[(b0 + bl) * 160 + t];
#pragma unroll
            for (int ii = 0; ii < 8; ++ii) {
                const float* p = &pcl[bl][ii * 8];
                float u = DOT8(w[ii][0], w[ii][1], p);
                float pr = u * vv;
                pr += __shfl_xor(pr, 1, 16);
                pr += __shfl_xor(pr, 2, 16);
                pr += __shfl_xor(pr, 4, 16);
                pr += __shfl_xor(pr, 8, 16);
                if ((t & 15) == 0) uvl[ii][bl][j] = pr;
            }
        }
    }
    __syncthreads();
    if (t < 128) {
        int ii = t >> 4, bl = t & 15;
        float* uv = uvl[ii][bl];
        float mx = uv[0];
#pragma unroll
        for (int jj = 1; jj < 10; ++jj) mx = fmaxf(mx, uv[jj]);
        float sum = 0.f;
        float ex[10];
#pragma unroll
        for (int jj = 0; jj < 10; ++jj) { ex[jj] = expf(uv[jj] - mx); sum += ex[jj]; }
        float inv = 1.f / sum;
#pragma unroll
        for (int jj = 0; jj < 10; ++jj) uv[jj] = ex[jj] * inv;
    }
    __syncthreads();
    if (t >= 160) return;
    for (int bl = 0; bl < 16; ++bl) {
        float acc = 0.f;
#pragma unroll
        for (int ii = 0; ii < 8; ++ii) {
            const float* p = &pcl[bl][ii * 8];
            float u = DOT8(w[ii][0], w[ii][1], p);
            acc += uvl[ii][bl][j] * u;
        }
        s2p[(size_t)ic * 20480 + (b0 + bl) * 160 + t] = acc;
    }
}

// -------- v2 + norm + mask, coalesced thread-per-output -------------------------
__global__ __launch_bounds__(256) void v2red_kernel(const float* __restrict__ s2p,
        const int* __restrict__ target, float* __restrict__ h0,
        float* __restrict__ nrm, float* __restrict__ out) {
    int gid = blockIdx.x * 256 + threadIdx.x;    // 0..20479
    int d = gid & 15, bj = gid >> 4;
    int j = bj % 10, b = bj / 10;
    float s = 0.f;
    for (int kc = 0; kc < 144; ++kc) s += s2p[(size_t)kc * 20480 + gid];
    float sq = s * s;
    sq += __shfl_xor(sq, 1, 16);
    sq += __shfl_xor(sq, 2, 16);
    sq += __shfl_xor(sq, 4, 16);
    sq += __shfl_xor(sq, 8, 16);
    float v = s * sq / ((1.f + sq) * sqrtf(sq + EPSQ));
    float vsq = v * v;
    vsq += __shfl_xor(vsq, 1, 16);
    vsq += __shfl_xor(vsq, 2, 16);
    vsq += __shfl_xor(vsq, 4, 16);
    vsq += __shfl_xor(vsq, 8, 16);
    float norm = sqrtf(vsq + EPSQ);
    h0[gid] = (j == target[b]) ? v : 0.f;
    if (d == 0) { nrm[b * 10 + j] = norm; out[b * 10 + j] = norm; }
}

// -------- fc1 with fused argmax (reads pre-masked h0) ---------------------------
__global__ __launch_bounds__(256) void fc1_kernel(const float* __restrict__ h0,
        const float* __restrict__ nrm, const float* __restrict__ w,
        const float* __restrict__ bias, float* __restrict__ ypred,
        float* __restrict__ h1) {
    int nc = blockIdx.x, b = blockIdx.y;
    int t = threadIdx.x;
    __shared__ float sk[160];
    if (t < 160) sk[t] = h0[b * 160 + t];
    __syncthreads();
    if (nc == 0 && t == 0) {
        float best = nrm[b * 10]; int am = 0;
#pragma unroll
        for (int jj = 1; jj < 10; ++jj) {
            float n2 = nrm[b * 10 + jj];
            if (n2 > best) { best = n2; am = jj; }
        }
        ypred[b] = (float)am;
    }
    int n = nc * 256 + t;
    float acc = bias[n];
    for (int k = 0; k < 160; ++k) acc += sk[k] * w[k * 512 + n];
    h1[(size_t)b * 512 + n] = fmaxf(acc, 0.f);
}

// -------- dense layers: relu (ACT=0) or sigmoid (ACT=1) -------------------------
template <int KDIM, int ACT>
__global__ __launch_bounds__(256) void fc_kernel(const float* __restrict__ in,
        const float* __restrict__ w, const float* __restrict__ bias,
        float* __restrict__ out, int N) {
    int b = blockIdx.y;
    int n = blockIdx.x * 256 + threadIdx.x;
    __shared__ float sk[KDIM];
    for (int r = threadIdx.x; r < KDIM; r += 256) sk[r] = in[(size_t)b * KDIM + r];
    __syncthreads();
    if (n >= N) return;
    float acc = bias[n];
    for (int k = 0; k < KDIM; ++k) acc += sk[k] * w[(size_t)k * N + n];
    if (ACT == 0) acc = fmaxf(acc, 0.f);
    else acc = 1.f / (1.f + expf(-acc));
    out[(size_t)b * N + n] = acc;
}

extern "C" void kernel_launch(void* const* d_in, const int* in_sizes, int n_in,
                              void* d_out, int out_size, void* d_ws, size_t ws_size,
                              hipStream_t stream) {
    const float* image = (const float*)d_in[0];
    const int*   target = (const int*)d_in[1];
    const float* w1  = (const float*)d_in[2];
    const float* b1  = (const float*)d_in[3];
    const float* w2  = (const float*)d_in[4];
    const float* b2  = (const float*)d_in[5];
    const float* Wm  = (const float*)d_in[6];
    const float* d1w = (const float*)d_in[7];
    const float* d1b = (const float*)d_in[8];
    const float* d2w = (const float*)d_in[9];
    const float* d2b = (const float*)d_in[10];
    const float* dow = (const float*)d_in[11];
    const float* dob = (const float*)d_in[12];
    float* out = (float*)d_out;
    float* ws  = (float*)d_ws;

    ushort* c1h  = (ushort*)(ws + WS_C1H);
    ushort* c1l  = (ushort*)(ws + WS_C1L);
    ushort* w2th = (ushort*)(ws + WS_W2TH);
    ushort* w2tl = (ushort*)(ws + WS_W2TL);

    int ksplit = 4;
    if (ws_size >= (size_t)(18415616 + 18 * 1179648) * 4) ksplit = 18;
    else if (ws_size >= (size_t)(18415616 + 12 * 1179648) * 4) ksplit = 12;
    else if (ws_size >= (size_t)(18415616 + 6 * 1179648) * 4) ksplit = 6;
    int nsteps = KSTEPS / ksplit / 2;
    int nwg = 144 * ksplit;

    convprep_kernel<<<3856, 256, 0, stream>>>(image, w1, b1, w2, c1h, c1l, w2th, w2tl);
    conv2_mfma_kernel<<<nwg, 256, 0, stream>>>(c1h, c1l, w2th, w2tl,
                                               ws + WS_CPART, nsteps, nwg);
    squash_pc_kernel<<<4608, 256, 0, stream>>>(ws + WS_CPART, b2, ws + WS_PC, ksplit);
    s1part_kernel<<<dim3(144, 8), 192, 0, stream>>>(Wm, ws + WS_PC, ws + WS_S1P);
    v1red_kernel<<<80, 256, 0, stream>>>(ws + WS_S1P, ws + WS_V1);
    c2s2_kernel<<<dim3(144, 8), 192, 0, stream>>>(Wm, ws + WS_PC, ws + WS_V1, ws + WS_S2P);
    v2red_kernel<<<80, 256, 0, stream>>>(ws + WS_S2P, target, ws + WS_H0,
                                         ws + WS_NRM, out);
    fc1_kernel<<<dim3(2, 128), 256, 0, stream>>>(ws + WS_H0, ws + WS_NRM,
                                                 d1w, d1b, out + 1280, ws + WS_H1);
    fc_kernel<512, 0><<<dim3(4, 128), 256, 0, stream>>>(ws + WS_H1, d2w, d2b, ws + WS_H2, 1024);
    fc_kernel<1024, 1><<<dim3(4, 128), 256, 0, stream>>>(ws + WS_H2, dow, dob, out + 1408, 784);
}

// Round 10
// 424.957 us; speedup vs baseline: 3.4235x; 1.1808x over previous
//
#include <hip/hip_runtime.h>
#include <hip/hip_bf16.h>

#define EPSQ 1e-7f

#define BSZ 128
#define M2 4608           // B*36 conv2 output positions
#define K2 20736          // 81*256
#define KSTEPS 648        // K2/32

// ws offsets in floats (liveness-overlapped).
// Phase 1 (conv): c1 hi/lo [0, 13,107,200), w2t hi/lo [13,107,200, 18,415,616),
//                 CPART [18,415,616, +ksplit*1,179,648)
// Phase 2 (routing): PC/S12ACC reuse dead-c1; H1/H2 reuse dead-w2t.
#define WS_C1H   0
#define WS_C1L   6553600
#define WS_W2TH  13107200
#define WS_W2TL  15761408
#define WS_CPART 18415616
#define WS_PC    0              // 1,179,648 fl
#define WS_S12A  1179648        // 40,960 fl: s1acc [0,20480) + s2acc [20480,40960)
#define WS_H1    13107200       // 65,536 (w2t dead)
#define WS_H2    13172736       // 131,072

typedef __attribute__((ext_vector_type(8))) short short8;
typedef __attribute__((ext_vector_type(4))) float floatx4;

#define DOT8(W0, W1, P) ((W0).x*(P)[0] + (W0).y*(P)[1] + (W0).z*(P)[2] + (W0).w*(P)[3] + \
                         (W1).x*(P)[4] + (W1).y*(P)[5] + (W1).z*(P)[6] + (W1).w*(P)[7])

__device__ inline ushort bf16_rne(float x) {
    union { float f; unsigned u; } v; v.f = x;
    unsigned r = v.u + 0x7FFFu + ((v.u >> 16) & 1u);
    return (ushort)(r >> 16);
}
__device__ inline float bf16_to_f(ushort h) {
    union { unsigned u; float f; } v; v.u = ((unsigned)h) << 16;
    return v.f;
}

// ---------------- fused conv1 (blocks [0,2560)) + w2 transpose ([2560,3856)) ----
__global__ __launch_bounds__(256) void convprep_kernel(const float* __restrict__ img,
        const float* __restrict__ w1, const float* __restrict__ b1,
        const float* __restrict__ w2,
        ushort* __restrict__ c1h, ushort* __restrict__ c1l,
        ushort* __restrict__ w2th, ushort* __restrict__ w2tl) {
    __shared__ float sm[4160];
    int t = threadIdx.x;
    int bid = blockIdx.x;
    if (bid < 2560) {
        int b = bid / 20, oh = bid % 20;
        if (t < 252) sm[t] = img[b * 784 + oh * 28 + t];
        __syncthreads();
        float acc[20];
#pragma unroll
        for (int ow = 0; ow < 20; ++ow) acc[ow] = 0.f;
        for (int kh = 0; kh < 9; ++kh) {
            float row[28];
#pragma unroll
            for (int c = 0; c < 28; ++c) row[c] = sm[kh * 28 + c];
#pragma unroll
            for (int kw = 0; kw < 9; ++kw) {
                float wv = w1[(kh * 9 + kw) * 256 + t];
#pragma unroll
                for (int ow = 0; ow < 20; ++ow) acc[ow] += row[kw + ow] * wv;
            }
        }
        float bias = b1[t];
        size_t opos = ((size_t)(b * 20 + oh) * 20) * 256 + t;
#pragma unroll
        for (int ow = 0; ow < 20; ++ow) {
            float x = fmaxf(acc[ow] + bias, 0.f);
            ushort h = bf16_rne(x);
            c1h[opos + (size_t)ow * 256] = h;
            c1l[opos + (size_t)ow * 256] = bf16_rne(x - bf16_to_f(h));
        }
    } else {
        int pb = bid - 2560;                 // 1296 = 324 kt x 4 nt
        int kt = pb >> 2, nt = pb & 3;
        int tn = t & 63, t4 = t >> 6;
#pragma unroll
        for (int i = 0; i < 16; ++i) {
            int k = i * 4 + t4;
            sm[k * 65 + tn] = w2[(size_t)(kt * 64 + k) * 256 + nt * 64 + tn];
        }
        __syncthreads();
        int tk = t & 63;
#pragma unroll
        for (int i = 0; i < 16; ++i) {
            int n = i * 4 + t4;
            float x = sm[tk * 65 + n];
            ushort h = bf16_rne(x);
            ushort lo = bf16_rne(x - bf16_to_f(h));
            size_t o = (size_t)(nt * 64 + n) * 20736 + kt * 64 + tk;
            w2th[o] = h; w2tl[o] = lo;
        }
    }
}

// -------- conv2 MFMA GEMM; epilogue now LDS-staged for full-line coalesced C ----
#define LDS_AH 0
#define LDS_AL 4096
#define LDS_BH 8192
#define LDS_BL 16384
__global__ __launch_bounds__(256) void conv2_mfma_kernel(
        const ushort* __restrict__ c1h, const ushort* __restrict__ c1l,
        const ushort* __restrict__ w2th, const ushort* __restrict__ w2tl,
        float* __restrict__ part, int nsteps, int nwg) {
    int bid = blockIdx.x;
    int v = (bid & 7) * (nwg >> 3) + (bid >> 3);   // bijective: 8 | nwg
    int mt = v % 72, grp = v / 72;
    int nt = grp & 1, ks = grp >> 1;
    int t = threadIdx.x;
    int m0 = mt * 64, n0 = nt * 128;
    __shared__ __attribute__((aligned(16))) ushort lds[24576];   // 48 KB

    int sr = t >> 3, sc = t & 7;
    int mA0 = m0 + sr, mA1 = m0 + sr + 32;
    int b0_ = mA0 / 36, r0_ = mA0 % 36;
    int b1_ = mA1 / 36, r1_ = mA1 % 36;
    int pb0 = ((b0_ * 20 + (r0_ / 6) * 2) * 20 + (r0_ % 6) * 2) * 256;
    int pb1 = ((b1_ * 20 + (r1_ / 6) * 2) * 20 + (r1_ % 6) * 2) * 256;
    size_t wb = (size_t)(n0 + sr) * 20736 + sc * 8;
    int wOff = sr * 64 + ((sc ^ (sr & 7)) * 8);

    int lane = t & 63, wave = t >> 6;
    int l15 = lane & 15, g = lane >> 4;
    int wrb = (wave >> 1) * 32, wcb = (wave & 1) * 64;

    floatx4 acc[2][4];
#pragma unroll
    for (int mi = 0; mi < 2; ++mi)
#pragma unroll
        for (int nj = 0; nj < 4; ++nj) acc[mi][nj] = (floatx4)0.f;

    int st0 = ks * nsteps;
    uint4 A0h, A1h, A0l, A1l, B0h, B1h, B2h, B3h, B0l, B1l, B2l, B3l;
#define LOADG64(ST) { \
        int kb = (ST) * 64; \
        int khkw = kb >> 8; int kh = khkw / 9, kw = khkw - kh * 9; \
        int ao = (kh * 20 + kw) * 256 + (kb & 255) + sc * 8; \
        A0h = *(const uint4*)(c1h + pb0 + ao); \
        A1h = *(const uint4*)(c1h + pb1 + ao); \
        A0l = *(const uint4*)(c1l + pb0 + ao); \
        A1l = *(const uint4*)(c1l + pb1 + ao); \
        size_t bo = wb + kb; \
        B0h = *(const uint4*)(w2th + bo); \
        B1h = *(const uint4*)(w2th + bo + (size_t)32 * 20736); \
        B2h = *(const uint4*)(w2th + bo + (size_t)64 * 20736); \
        B3h = *(const uint4*)(w2th + bo + (size_t)96 * 20736); \
        B0l = *(const uint4*)(w2tl + bo); \
        B1l = *(const uint4*)(w2tl + bo + (size_t)32 * 20736); \
        B2l = *(const uint4*)(w2tl + bo + (size_t)64 * 20736); \
        B3l = *(const uint4*)(w2tl + bo + (size_t)96 * 20736); }

    LOADG64(st0);
    for (int st = 0; st < nsteps; ++st) {
        __syncthreads();
        *(uint4*)&lds[LDS_AH + wOff]        = A0h;
        *(uint4*)&lds[LDS_AH + wOff + 2048] = A1h;
        *(uint4*)&lds[LDS_AL + wOff]        = A0l;
        *(uint4*)&lds[LDS_AL + wOff + 2048] = A1l;
        *(uint4*)&lds[LDS_BH + wOff]        = B0h;
        *(uint4*)&lds[LDS_BH + wOff + 2048] = B1h;
        *(uint4*)&lds[LDS_BH + wOff + 4096] = B2h;
        *(uint4*)&lds[LDS_BH + wOff + 6144] = B3h;
        *(uint4*)&lds[LDS_BL + wOff]        = B0l;
        *(uint4*)&lds[LDS_BL + wOff + 2048] = B1l;
        *(uint4*)&lds[LDS_BL + wOff + 4096] = B2l;
        *(uint4*)&lds[LDS_BL + wOff + 6144] = B3l;
        __syncthreads();
        if (st + 1 < nsteps) LOADG64(st0 + st + 1);

#pragma unroll
        for (int kk = 0; kk < 2; ++kk) {
            int sl = kk * 4 + g;
            short8 ah[2], al[2], bh[4], bl[4];
#pragma unroll
            for (int mi = 0; mi < 2; ++mi) {
                int r = wrb + mi * 16 + l15;
                int ro = r * 64 + ((sl ^ (r & 7)) * 8);
                ah[mi] = *(const short8*)&lds[LDS_AH + ro];
                al[mi] = *(const short8*)&lds[LDS_AL + ro];
            }
#pragma unroll
            for (int nj = 0; nj < 4; ++nj) {
                int c = wcb + nj * 16 + l15;
                int co = c * 64 + ((sl ^ (c & 7)) * 8);
                bh[nj] = *(const short8*)&lds[LDS_BH + co];
                bl[nj] = *(const short8*)&lds[LDS_BL + co];
            }
#pragma unroll
            for (int mi = 0; mi < 2; ++mi)
#pragma unroll
                for (int nj = 0; nj < 4; ++nj) {
                    acc[mi][nj] = __builtin_amdgcn_mfma_f32_16x16x32_bf16(ah[mi], bh[nj], acc[mi][nj], 0, 0, 0);
                    acc[mi][nj] = __builtin_amdgcn_mfma_f32_16x16x32_bf16(ah[mi], bl[nj], acc[mi][nj], 0, 0, 0);
                    acc[mi][nj] = __builtin_amdgcn_mfma_f32_16x16x32_bf16(al[mi], bh[nj], acc[mi][nj], 0, 0, 0);
                }
        }
    }
    // epilogue: stage C tile in LDS (row pad 132 -> conflict-lite), then
    // fully-coalesced float4 stores (512 B contiguous per row per block).
    __syncthreads();
    float* ldsf = (float*)lds;
#pragma unroll
    for (int mi = 0; mi < 2; ++mi)
#pragma unroll
        for (int nj = 0; nj < 4; ++nj) {
            int col = wcb + nj * 16 + l15;
            int rw = wrb + mi * 16 + (lane >> 4) * 4;
#pragma unroll
            for (int r = 0; r < 4; ++r)
                ldsf[(rw + r) * 132 + col] = acc[mi][nj][r];
        }
    __syncthreads();
    size_t obase = (size_t)ks * M2 * 256;
#pragma unroll
    for (int i = 0; i < 8; ++i) {
        int f = i * 256 + t;          // float4 id 0..2047
        int row = f >> 5, c4 = f & 31;
        float4 val = *(const float4*)&ldsf[row * 132 + c4 * 4];
        *(float4*)&part[obase + (size_t)(m0 + row) * 256 + n0 + c4 * 4] = val;
    }
}

// -------- reduce k-split partials + bias + relu + squash(8) -> pc; zero s12acc --
__global__ __launch_bounds__(256) void squash_pc_kernel(const float* __restrict__ part,
        const float* __restrict__ b2, float* __restrict__ pc,
        float* __restrict__ s12acc, int nsplit) {
    int m = blockIdx.x;
    int n = threadIdx.x;
    if (m < 160) s12acc[m * 256 + n] = 0.f;   // zero s1acc+s2acc (40960 fl)
    size_t idx = (size_t)m * 256 + n;
    const size_t stride = (size_t)M2 * 256;
    float v = 0.f;
    for (int s = 0; s < nsplit; ++s) v += part[idx + s * stride];
    v = fmaxf(v + b2[n], 0.f);
    float sq = v * v;
    sq += __shfl_xor(sq, 1, 8);
    sq += __shfl_xor(sq, 2, 8);
    sq += __shfl_xor(sq, 4, 8);
    float scale = sq / ((1.f + sq) * sqrtf(sq + EPSQ));
    pc[idx] = v * scale;
}

// -------- s1: grid (144 x 8), W in regs, atomic accumulation into s1acc ---------
__global__ __launch_bounds__(192) void s1part_kernel(const float* __restrict__ Wm,
        const float* __restrict__ pc, float* __restrict__ s1acc) {
    int ic = blockIdx.x, bg = blockIdx.y;
    int i0 = ic * 8, b0 = bg * 16;
    int t = threadIdx.x;
    __shared__ float pcl[16][68];
    for (int e = t; e < 1024; e += 192) {
        int bl = e >> 6, off = e & 63;
        pcl[bl][off] = pc[(size_t)(b0 + bl) * 9216 + i0 * 8 + off];
    }
    __syncthreads();
    if (t >= 160) return;
    float4 w[8][2];
#pragma unroll
    for (int ii = 0; ii < 8; ++ii) {
        const float4* wp = (const float4*)&Wm[(size_t)(i0 + ii) * 1280 + t * 8];
        w[ii][0] = wp[0]; w[ii][1] = wp[1];
    }
    for (int bl = 0; bl < 16; ++bl) {
        float s = 0.f;
#pragma unroll
        for (int ii = 0; ii < 8; ++ii) {
            const float* p = &pcl[bl][ii * 8];
            s += DOT8(w[ii][0], w[ii][1], p);
        }
        atomicAdd(&s1acc[(b0 + bl) * 160 + t], s);
    }
}

// -------- c2s2: v1 squash folded in; agreement+softmax; atomic s2 accumulation --
__global__ __launch_bounds__(192) void c2s2_kernel(const float* __restrict__ Wm,
        const float* __restrict__ pc, const float* __restrict__ s1acc,
        float* __restrict__ s2acc) {
    int ic = blockIdx.x, bg = blockIdx.y;
    int i0 = ic * 8, b0 = bg * 16;
    int t = threadIdx.x;
    __shared__ float pcl[16][68];
    __shared__ float uvl[8][16][10];
    for (int e = t; e < 1024; e += 192) {
        int bl = e >> 6, off = e & 63;
        pcl[bl][off] = pc[(size_t)(b0 + bl) * 9216 + i0 * 8 + off];
    }
    __syncthreads();
    int j = t >> 4;
    float4 w[8][2];
    if (t < 160) {
#pragma unroll
        for (int ii = 0; ii < 8; ++ii) {
            const float4* wp = (const float4*)&Wm[(size_t)(i0 + ii) * 1280 + t * 8];
            w[ii][0] = wp[0]; w[ii][1] = wp[1];
        }
        for (int bl = 0; bl < 16; ++bl) {
            float s1v = s1acc[(b0 + bl) * 160 + t] * 0.1f;
            float q = s1v * s1v;
            q += __shfl_xor(q, 1, 16);
            q += __shfl_xor(q, 2, 16);
            q += __shfl_xor(q, 4, 16);
            q += __shfl_xor(q, 8, 16);
            float vv = s1v * q / ((1.f + q) * sqrtf(q + EPSQ));
#pragma unroll
            for (int ii = 0; ii < 8; ++ii) {
                const float* p = &pcl[bl][ii * 8];
                float u = DOT8(w[ii][0], w[ii][1], p);
                float pr = u * vv;
                pr += __shfl_xor(pr, 1, 16);
                pr += __shfl_xor(pr, 2, 16);
                pr += __shfl_xor(pr, 4, 16);
                pr += __shfl_xor(pr, 8, 16);
                if ((t & 15) == 0) uvl[ii][bl][j] = pr;
            }
        }
    }
    __syncthreads();
    if (t < 128) {
        int ii = t >> 4, bl = t & 15;
        float* uv = uvl[ii][bl];
        float mx = uv[0];
#pragma unroll
        for (int jj = 1; jj < 10; ++jj) mx = fmaxf(mx, uv[jj]);
        float sum = 0.f;
        float ex[10];
#pragma unroll
        for (int jj = 0; jj < 10; ++jj) { ex[jj] = expf(uv[jj] - mx); sum += ex[jj]; }
        float inv = 1.f / sum;
#pragma unroll
        for (int jj = 0; jj < 10; ++jj) uv[jj] = ex[jj] * inv;
    }
    __syncthreads();
    if (t >= 160) return;
    for (int bl = 0; bl < 16; ++bl) {
        float acc = 0.f;
#pragma unroll
        for (int ii = 0; ii < 8; ++ii) {
            const float* p = &pcl[bl][ii * 8];
            float u = DOT8(w[ii][0], w[ii][1], p);
            acc += uvl[ii][bl][j] * u;
        }
        atomicAdd(&s2acc[(b0 + bl) * 160 + t], acc);
    }
}

// -------- fc1 with fused v2-squash, norms, argmax, target mask ------------------
__global__ __launch_bounds__(256) void fc1_kernel(const float* __restrict__ s2acc,
        const int* __restrict__ target, const float* __restrict__ w,
        const float* __restrict__ bias, float* __restrict__ out,
        float* __restrict__ h1) {
    int nc = blockIdx.x, b = blockIdx.y;
    int t = threadIdx.x;
    __shared__ float sk[160];
    __shared__ float nl[10];
    if (t < 160) {
        float s = s2acc[b * 160 + t];
        float sq = s * s;
        sq += __shfl_xor(sq, 1, 16);
        sq += __shfl_xor(sq, 2, 16);
        sq += __shfl_xor(sq, 4, 16);
        sq += __shfl_xor(sq, 8, 16);
        float v = s * sq / ((1.f + sq) * sqrtf(sq + EPSQ));
        float vsq = v * v;
        vsq += __shfl_xor(vsq, 1, 16);
        vsq += __shfl_xor(vsq, 2, 16);
        vsq += __shfl_xor(vsq, 4, 16);
        vsq += __shfl_xor(vsq, 8, 16);
        float norm = sqrtf(vsq + EPSQ);
        int j = t >> 4;
        sk[t] = (j == target[b]) ? v : 0.f;
        if ((t & 15) == 0) {
            nl[j] = norm;
            if (nc == 0) out[b * 10 + j] = norm;
        }
    }
    __syncthreads();
    if (nc == 0 && t == 0) {
        float best = nl[0]; int am = 0;
#pragma unroll
        for (int jj = 1; jj < 10; ++jj) if (nl[jj] > best) { best = nl[jj]; am = jj; }
        out[1280 + b] = (float)am;
    }
    int n = nc * 256 + t;
    float acc = bias[n];
    for (int k = 0; k < 160; ++k) acc += sk[k] * w[k * 512 + n];
    h1[(size_t)b * 512 + n] = fmaxf(acc, 0.f);
}

// -------- dense layers: relu (ACT=0) or sigmoid (ACT=1) -------------------------
template <int KDIM, int ACT>
__global__ __launch_bounds__(256) void fc_kernel(const float* __restrict__ in,
        const float* __restrict__ w, const float* __restrict__ bias,
        float* __restrict__ out, int N) {
    int b = blockIdx.y;
    int n = blockIdx.x * 256 + threadIdx.x;
    __shared__ float sk[KDIM];
    for (int r = threadIdx.x; r < KDIM; r += 256) sk[r] = in[(size_t)b * KDIM + r];
    __syncthreads();
    if (n >= N) return;
    float acc = bias[n];
    for (int k = 0; k < KDIM; ++k) acc += sk[k] * w[(size_t)k * N + n];
    if (ACT == 0) acc = fmaxf(acc, 0.f);
    else acc = 1.f / (1.f + expf(-acc));
    out[(size_t)b * N + n] = acc;
}

extern "C" void kernel_launch(void* const* d_in, const int* in_sizes, int n_in,
                              void* d_out, int out_size, void* d_ws, size_t ws_size,
                              hipStream_t stream) {
    const float* image = (const float*)d_in[0];
    const int*   target = (const int*)d_in[1];
    const float* w1  = (const float*)d_in[2];
    const float* b1  = (const float*)d_in[3];
    const float* w2  = (const float*)d_in[4];
    const float* b2  = (const float*)d_in[5];
    const float* Wm  = (const float*)d_in[6];
    const float* d1w = (const float*)d_in[7];
    const float* d1b = (const float*)d_in[8];
    const float* d2w = (const float*)d_in[9];
    const float* d2b = (const float*)d_in[10];
    const float* dow = (const float*)d_in[11];
    const float* dob = (const float*)d_in[12];
    float* out = (float*)d_out;
    float* ws  = (float*)d_ws;

    ushort* c1h  = (ushort*)(ws + WS_C1H);
    ushort* c1l  = (ushort*)(ws + WS_C1L);
    ushort* w2th = (ushort*)(ws + WS_W2TH);
    ushort* w2tl = (ushort*)(ws + WS_W2TL);

    int ksplit = 4;
    if (ws_size >= (size_t)(18415616 + 18 * 1179648) * 4) ksplit = 18;
    else if (ws_size >= (size_t)(18415616 + 12 * 1179648) * 4) ksplit = 12;
    else if (ws_size >= (size_t)(18415616 + 6 * 1179648) * 4) ksplit = 6;
    int nsteps = KSTEPS / ksplit / 2;
    int nwg = 144 * ksplit;

    float* s1acc = ws + WS_S12A;
    float* s2acc = ws + WS_S12A + 20480;

    convprep_kernel<<<3856, 256, 0, stream>>>(image, w1, b1, w2, c1h, c1l, w2th, w2tl);
    conv2_mfma_kernel<<<nwg, 256, 0, stream>>>(c1h, c1l, w2th, w2tl,
                                               ws + WS_CPART, nsteps, nwg);
    squash_pc_kernel<<<4608, 256, 0, stream>>>(ws + WS_CPART, b2, ws + WS_PC,
                                               ws + WS_S12A, ksplit);
    s1part_kernel<<<dim3(144, 8), 192, 0, stream>>>(Wm, ws + WS_PC, s1acc);
    c2s2_kernel<<<dim3(144, 8), 192, 0, stream>>>(Wm, ws + WS_PC, s1acc, s2acc);
    fc1_kernel<<<dim3(2, 128), 256, 0, stream>>>(s2acc, target, d1w, d1b,
                                                 out, ws + WS_H1);
    fc_kernel<512, 0><<<dim3(4, 128), 256, 0, stream>>>(ws + WS_H1, d2w, d2b, ws + WS_H2, 1024);
    fc_kernel<1024, 1><<<dim3(4, 128), 256, 0, stream>>>(ws + WS_H2, dow, dob, out + 1408, 784);
}

// Round 12
// 415.031 us; speedup vs baseline: 3.5054x; 1.0239x over previous
//
#include <hip/hip_runtime.h>
#include <hip/hip_bf16.h>

#define EPSQ 1e-7f

#define BSZ 128
#define M2 4608           // B*36 conv2 output positions
#define K2 20736          // 81*256
#define KSTEPS 648        // K2/32

// ws offsets in floats (liveness-overlapped).
#define WS_C1H   0
#define WS_C1L   6553600
#define WS_W2TH  13107200
#define WS_W2TL  15761408
#define WS_CPART 18415616
#define WS_PC    0              // 1,179,648 fl (c1 dead after conv2)
#define WS_S12A  1179648        // 40,960 fl: s1acc [0,20480) + s2acc [20480,40960)
#define WS_H1    13107200       // 65,536 (w2t dead)
#define WS_H2    13172736       // 131,072

typedef __attribute__((ext_vector_type(8))) short short8;
typedef __attribute__((ext_vector_type(4))) float floatx4;

#define DOT8(W0, W1, P) ((W0).x*(P)[0] + (W0).y*(P)[1] + (W0).z*(P)[2] + (W0).w*(P)[3] + \
                         (W1).x*(P)[4] + (W1).y*(P)[5] + (W1).z*(P)[6] + (W1).w*(P)[7])

__device__ inline ushort bf16_rne(float x) {
    union { float f; unsigned u; } v; v.f = x;
    unsigned r = v.u + 0x7FFFu + ((v.u >> 16) & 1u);
    return (ushort)(r >> 16);
}
__device__ inline float bf16_to_f(ushort h) {
    union { unsigned u; float f; } v; v.u = ((unsigned)h) << 16;
    return v.f;
}

// ---------------- fused conv1 (blocks [0,2560)) + w2 transpose ([2560,3856)) ----
__global__ __launch_bounds__(256) void convprep_kernel(const float* __restrict__ img,
        const float* __restrict__ w1, const float* __restrict__ b1,
        const float* __restrict__ w2,
        ushort* __restrict__ c1h, ushort* __restrict__ c1l,
        ushort* __restrict__ w2th, ushort* __restrict__ w2tl) {
    __shared__ float sm[4160];
    int t = threadIdx.x;
    int bid = blockIdx.x;
    if (bid < 2560) {
        int b = bid / 20, oh = bid % 20;
        if (t < 252) sm[t] = img[b * 784 + oh * 28 + t];
        __syncthreads();
        float acc[20];
#pragma unroll
        for (int ow = 0; ow < 20; ++ow) acc[ow] = 0.f;
        for (int kh = 0; kh < 9; ++kh) {
            float row[28];
#pragma unroll
            for (int c = 0; c < 28; ++c) row[c] = sm[kh * 28 + c];
#pragma unroll
            for (int kw = 0; kw < 9; ++kw) {
                float wv = w1[(kh * 9 + kw) * 256 + t];
#pragma unroll
                for (int ow = 0; ow < 20; ++ow) acc[ow] += row[kw + ow] * wv;
            }
        }
        float bias = b1[t];
        size_t opos = ((size_t)(b * 20 + oh) * 20) * 256 + t;
#pragma unroll
        for (int ow = 0; ow < 20; ++ow) {
            float x = fmaxf(acc[ow] + bias, 0.f);
            ushort h = bf16_rne(x);
            c1h[opos + (size_t)ow * 256] = h;
            c1l[opos + (size_t)ow * 256] = bf16_rne(x - bf16_to_f(h));
        }
    } else {
        int pb = bid - 2560;                 // 1296 = 324 kt x 4 nt
        int kt = pb >> 2, nt = pb & 3;
        int tn = t & 63, t4 = t >> 6;
#pragma unroll
        for (int i = 0; i < 16; ++i) {
            int k = i * 4 + t4;
            sm[k * 65 + tn] = w2[(size_t)(kt * 64 + k) * 256 + nt * 64 + tn];
        }
        __syncthreads();
        int tk = t & 63;
#pragma unroll
        for (int i = 0; i < 16; ++i) {
            int n = i * 4 + t4;
            float x = sm[tk * 65 + n];
            ushort h = bf16_rne(x);
            ushort lo = bf16_rne(x - bf16_to_f(h));
            size_t o = (size_t)(nt * 64 + n) * 20736 + kt * 64 + tk;
            w2th[o] = h; w2tl[o] = lo;
        }
    }
}

// -------- conv2 MFMA GEMM (R6-verified core; LDS-staged coalesced epilogue) -----
#define LDS_AH 0
#define LDS_AL 4096
#define LDS_BH 8192
#define LDS_BL 16384
__global__ __launch_bounds__(256) void conv2_mfma_kernel(
        const ushort* __restrict__ c1h, const ushort* __restrict__ c1l,
        const ushort* __restrict__ w2th, const ushort* __restrict__ w2tl,
        float* __restrict__ part, int nsteps, int nwg) {
    int bid = blockIdx.x;
    int v = (bid & 7) * (nwg >> 3) + (bid >> 3);   // bijective: 8 | nwg
    int mt = v % 72, grp = v / 72;
    int nt = grp & 1, ks = grp >> 1;
    int t = threadIdx.x;
    int m0 = mt * 64, n0 = nt * 128;
    __shared__ __attribute__((aligned(16))) ushort lds[24576];   // 48 KB

    int sr = t >> 3, sc = t & 7;
    int mA0 = m0 + sr, mA1 = m0 + sr + 32;
    int b0_ = mA0 / 36, r0_ = mA0 % 36;
    int b1_ = mA1 / 36, r1_ = mA1 % 36;
    int pb0 = ((b0_ * 20 + (r0_ / 6) * 2) * 20 + (r0_ % 6) * 2) * 256;
    int pb1 = ((b1_ * 20 + (r1_ / 6) * 2) * 20 + (r1_ % 6) * 2) * 256;
    size_t wb = (size_t)(n0 + sr) * 20736 + sc * 8;
    int wOff = sr * 64 + ((sc ^ (sr & 7)) * 8);

    int lane = t & 63, wave = t >> 6;
    int l15 = lane & 15, g = lane >> 4;
    int wrb = (wave >> 1) * 32, wcb = (wave & 1) * 64;

    floatx4 acc[2][4];
#pragma unroll
    for (int mi = 0; mi < 2; ++mi)
#pragma unroll
        for (int nj = 0; nj < 4; ++nj) acc[mi][nj] = (floatx4)0.f;

    int st0 = ks * nsteps;
    uint4 A0h, A1h, A0l, A1l, B0h, B1h, B2h, B3h, B0l, B1l, B2l, B3l;
#define LOADG64(ST) { \
        int kb = (ST) * 64; \
        int khkw = kb >> 8; int kh = khkw / 9, kw = khkw - kh * 9; \
        int ao = (kh * 20 + kw) * 256 + (kb & 255) + sc * 8; \
        A0h = *(const uint4*)(c1h + pb0 + ao); \
        A1h = *(const uint4*)(c1h + pb1 + ao); \
        A0l = *(const uint4*)(c1l + pb0 + ao); \
        A1l = *(const uint4*)(c1l + pb1 + ao); \
        size_t bo = wb + kb; \
        B0h = *(const uint4*)(w2th + bo); \
        B1h = *(const uint4*)(w2th + bo + (size_t)32 * 20736); \
        B2h = *(const uint4*)(w2th + bo + (size_t)64 * 20736); \
        B3h = *(const uint4*)(w2th + bo + (size_t)96 * 20736); \
        B0l = *(const uint4*)(w2tl + bo); \
        B1l = *(const uint4*)(w2tl + bo + (size_t)32 * 20736); \
        B2l = *(const uint4*)(w2tl + bo + (size_t)64 * 20736); \
        B3l = *(const uint4*)(w2tl + bo + (size_t)96 * 20736); }

    LOADG64(st0);
    for (int st = 0; st < nsteps; ++st) {
        __syncthreads();
        *(uint4*)&lds[LDS_AH + wOff]        = A0h;
        *(uint4*)&lds[LDS_AH + wOff + 2048] = A1h;
        *(uint4*)&lds[LDS_AL + wOff]        = A0l;
        *(uint4*)&lds[LDS_AL + wOff + 2048] = A1l;
        *(uint4*)&lds[LDS_BH + wOff]        = B0h;
        *(uint4*)&lds[LDS_BH + wOff + 2048] = B1h;
        *(uint4*)&lds[LDS_BH + wOff + 4096] = B2h;
        *(uint4*)&lds[LDS_BH + wOff + 6144] = B3h;
        *(uint4*)&lds[LDS_BL + wOff]        = B0l;
        *(uint4*)&lds[LDS_BL + wOff + 2048] = B1l;
        *(uint4*)&lds[LDS_BL + wOff + 4096] = B2l;
        *(uint4*)&lds[LDS_BL + wOff + 6144] = B3l;
        __syncthreads();
        if (st + 1 < nsteps) LOADG64(st0 + st + 1);

#pragma unroll
        for (int kk = 0; kk < 2; ++kk) {
            int sl = kk * 4 + g;
            short8 ah[2], al[2], bh[4], bl[4];
#pragma unroll
            for (int mi = 0; mi < 2; ++mi) {
                int r = wrb + mi * 16 + l15;
                int ro = r * 64 + ((sl ^ (r & 7)) * 8);
                ah[mi] = *(const short8*)&lds[LDS_AH + ro];
                al[mi] = *(const short8*)&lds[LDS_AL + ro];
            }
#pragma unroll
            for (int nj = 0; nj < 4; ++nj) {
                int c = wcb + nj * 16 + l15;
                int co = c * 64 + ((sl ^ (c & 7)) * 8);
                bh[nj] = *(const short8*)&lds[LDS_BH + co];
                bl[nj] = *(const short8*)&lds[LDS_BL + co];
            }
#pragma unroll
            for (int mi = 0; mi < 2; ++mi)
#pragma unroll
                for (int nj = 0; nj < 4; ++nj) {
                    acc[mi][nj] = __builtin_amdgcn_mfma_f32_16x16x32_bf16(ah[mi], bh[nj], acc[mi][nj], 0, 0, 0);
                    acc[mi][nj] = __builtin_amdgcn_mfma_f32_16x16x32_bf16(ah[mi], bl[nj], acc[mi][nj], 0, 0, 0);
                    acc[mi][nj] = __builtin_amdgcn_mfma_f32_16x16x32_bf16(al[mi], bh[nj], acc[mi][nj], 0, 0, 0);
                }
        }
    }
    __syncthreads();
    float* ldsf = (float*)lds;
#pragma unroll
    for (int mi = 0; mi < 2; ++mi)
#pragma unroll
        for (int nj = 0; nj < 4; ++nj) {
            int col = wcb + nj * 16 + l15;
            int rw = wrb + mi * 16 + (lane >> 4) * 4;
#pragma unroll
            for (int r = 0; r < 4; ++r)
                ldsf[(rw + r) * 132 + col] = acc[mi][nj][r];
        }
    __syncthreads();
    size_t obase = (size_t)ks * M2 * 256;
#pragma unroll
    for (int i = 0; i < 8; ++i) {
        int f = i * 256 + t;          // float4 id 0..2047
        int row = f >> 5, c4 = f & 31;
        float4 val = *(const float4*)&ldsf[row * 132 + c4 * 4];
        *(float4*)&part[obase + (size_t)(m0 + row) * 256 + n0 + c4 * 4] = val;
    }
}

// -------- reduce k-split partials + bias + relu + squash(8) -> pc; zero s12acc --
__global__ __launch_bounds__(256) void squash_pc_kernel(const float* __restrict__ part,
        const float* __restrict__ b2, float* __restrict__ pc,
        float* __restrict__ s12acc, int nsplit) {
    int m = blockIdx.x;
    int n = threadIdx.x;
    if (m < 160) s12acc[m * 256 + n] = 0.f;   // zero s1acc+s2acc (40960 fl)
    size_t idx = (size_t)m * 256 + n;
    const size_t stride = (size_t)M2 * 256;
    float v = 0.f;
    for (int s = 0; s < nsplit; ++s) v += part[idx + s * stride];
    v = fmaxf(v + b2[n], 0.f);
    float sq = v * v;
    sq += __shfl_xor(sq, 1, 8);
    sq += __shfl_xor(sq, 2, 8);
    sq += __shfl_xor(sq, 4, 8);
    float scale = sq / ((1.f + sq) * sqrtf(sq + EPSQ));
    pc[idx] = v * scale;
}

// -------- s1: grid (144 x 8), W in regs, atomic accumulation into s1acc ---------
__global__ __launch_bounds__(192) void s1part_kernel(const float* __restrict__ Wm,
        const float* __restrict__ pc, float* __restrict__ s1acc) {
    int ic = blockIdx.x, bg = blockIdx.y;
    int i0 = ic * 8, b0 = bg * 16;
    int t = threadIdx.x;
    __shared__ float pcl[16][68];
    for (int e = t; e < 1024; e += 192) {
        int bl = e >> 6, off = e & 63;
        pcl[bl][off] = pc[(size_t)(b0 + bl) * 9216 + i0 * 8 + off];
    }
    __syncthreads();
    if (t >= 160) return;
    float4 w[8][2];
#pragma unroll
    for (int ii = 0; ii < 8; ++ii) {
        const float4* wp = (const float4*)&Wm[(size_t)(i0 + ii) * 1280 + t * 8];
        w[ii][0] = wp[0]; w[ii][1] = wp[1];
    }
    for (int bl = 0; bl < 16; ++bl) {
        float s = 0.f;
#pragma unroll
        for (int ii = 0; ii < 8; ++ii) {
            const float* p = &pcl[bl][ii * 8];
            s += DOT8(w[ii][0], w[ii][1], p);
        }
        atomicAdd(&s1acc[(b0 + bl) * 160 + t], s);
    }
}

// -------- c2s2: v1 squash folded in; agreement+softmax; atomic s2 accumulation --
__global__ __launch_bounds__(192) void c2s2_kernel(const float* __restrict__ Wm,
        const float* __restrict__ pc, const float* __restrict__ s1acc,
        float* __restrict__ s2acc) {
    int ic = blockIdx.x, bg = blockIdx.y;
    int i0 = ic * 8, b0 = bg * 16;
    int t = threadIdx.x;
    __shared__ float pcl[16][68];
    __shared__ float uvl[8][16][10];
    for (int e = t; e < 1024; e += 192) {
        int bl = e >> 6, off = e & 63;
        pcl[bl][off] = pc[(size_t)(b0 + bl) * 9216 + i0 * 8 + off];
    }
    __syncthreads();
    int j = t >> 4;
    float4 w[8][2];
    if (t < 160) {
#pragma unroll
        for (int ii = 0; ii < 8; ++ii) {
            const float4* wp = (const float4*)&Wm[(size_t)(i0 + ii) * 1280 + t * 8];
            w[ii][0] = wp[0]; w[ii][1] = wp[1];
        }
        for (int bl = 0; bl < 16; ++bl) {
            float s1v = s1acc[(b0 + bl) * 160 + t] * 0.1f;
            float q = s1v * s1v;
            q += __shfl_xor(q, 1, 16);
            q += __shfl_xor(q, 2, 16);
            q += __shfl_xor(q, 4, 16);
            q += __shfl_xor(q, 8, 16);
            float vv = s1v * q / ((1.f + q) * sqrtf(q + EPSQ));
#pragma unroll
            for (int ii = 0; ii < 8; ++ii) {
                const float* p = &pcl[bl][ii * 8];
                float u = DOT8(w[ii][0], w[ii][1], p);
                float pr = u * vv;
                pr += __shfl_xor(pr, 1, 16);
                pr += __shfl_xor(pr, 2, 16);
                pr += __shfl_xor(pr, 4, 16);
                pr += __shfl_xor(pr, 8, 16);
                if ((t & 15) == 0) uvl[ii][bl][j] = pr;
            }
        }
    }
    __syncthreads();
    if (t < 128) {
        int ii = t >> 4, bl = t & 15;
        float* uv = uvl[ii][bl];
        float mx = uv[0];
#pragma unroll
        for (int jj = 1; jj < 10; ++jj) mx = fmaxf(mx, uv[jj]);
        float sum = 0.f;
        float ex[10];
#pragma unroll
        for (int jj = 0; jj < 10; ++jj) { ex[jj] = expf(uv[jj] - mx); sum += ex[jj]; }
        float inv = 1.f / sum;
#pragma unroll
        for (int jj = 0; jj < 10; ++jj) uv[jj] = ex[jj] * inv;
    }
    __syncthreads();
    if (t >= 160) return;
    for (int bl = 0; bl < 16; ++bl) {
        float acc = 0.f;
#pragma unroll
        for (int ii = 0; ii < 8; ++ii) {
            const float* p = &pcl[bl][ii * 8];
            float u = DOT8(w[ii][0], w[ii][1], p);
            acc += uvl[ii][bl][j] * u;
        }
        atomicAdd(&s2acc[(b0 + bl) * 160 + t], acc);
    }
}

// ======== batch-grouped decoder: weights read 32x instead of 128x ===============
#define DGRP 4

// -------- fc1: fused v2-squash/norm/argmax/mask preamble + GEMM -----------------
__global__ __launch_bounds__(256) void fc1_kernel(const float* __restrict__ s2acc,
        const int* __restrict__ target, const float* __restrict__ w,
        const float* __restrict__ bias, float* __restrict__ out,
        float* __restrict__ h1) {
    int nc = blockIdx.x;                 // 0..1
    int b0 = blockIdx.y * DGRP;
    int t = threadIdx.x;
    __shared__ float sk[DGRP][160];
    __shared__ float nl[DGRP][10];
    for (int bb = 0; bb < DGRP; ++bb) {
        if (t < 160) {
            int b = b0 + bb;
            float s = s2acc[b * 160 + t];
            float sq = s * s;
            sq += __shfl_xor(sq, 1, 16);
            sq += __shfl_xor(sq, 2, 16);
            sq += __shfl_xor(sq, 4, 16);
            sq += __shfl_xor(sq, 8, 16);
            float v = s * sq / ((1.f + sq) * sqrtf(sq + EPSQ));
            float vsq = v * v;
            vsq += __shfl_xor(vsq, 1, 16);
            vsq += __shfl_xor(vsq, 2, 16);
            vsq += __shfl_xor(vsq, 4, 16);
            vsq += __shfl_xor(vsq, 8, 16);
            float norm = sqrtf(vsq + EPSQ);
            int j = t >> 4;
            sk[bb][t] = (j == target[b]) ? v : 0.f;
            if ((t & 15) == 0) {
                nl[bb][j] = norm;
                if (nc == 0) out[b * 10 + j] = norm;
            }
        }
    }
    __syncthreads();
    if (nc == 0 && t < DGRP) {
        float best = nl[t][0]; int am = 0;
#pragma unroll
        for (int jj = 1; jj < 10; ++jj) if (nl[t][jj] > best) { best = nl[t][jj]; am = jj; }
        out[1280 + b0 + t] = (float)am;
    }
    int n = nc * 256 + t;
    float acc[DGRP];
#pragma unroll
    for (int bb = 0; bb < DGRP; ++bb) acc[bb] = bias[n];
    for (int k = 0; k < 160; ++k) {
        float wv = w[k * 512 + n];
#pragma unroll
        for (int bb = 0; bb < DGRP; ++bb) acc[bb] += sk[bb][k] * wv;
    }
#pragma unroll
    for (int bb = 0; bb < DGRP; ++bb)
        h1[(size_t)(b0 + bb) * 512 + n] = fmaxf(acc[bb], 0.f);
}

// -------- fc2: relu, batch-grouped ----------------------------------------------
__global__ __launch_bounds__(256) void fc2_kernel(const float* __restrict__ h1,
        const float* __restrict__ w, const float* __restrict__ bias,
        float* __restrict__ h2) {
    int nc = blockIdx.x;                 // 0..3
    int b0 = blockIdx.y * DGRP;
    int t = threadIdx.x;
    __shared__ float sk[DGRP][512];
    for (int e = t; e < DGRP * 512; e += 256) {
        int bb = e >> 9, k = e & 511;
        sk[bb][k] = h1[(size_t)(b0 + bb) * 512 + k];
    }
    __syncthreads();
    int n = nc * 256 + t;
    float acc[DGRP];
#pragma unroll
    for (int bb = 0; bb < DGRP; ++bb) acc[bb] = bias[n];
    for (int k = 0; k < 512; ++k) {
        float wv = w[(size_t)k * 1024 + n];
#pragma unroll
        for (int bb = 0; bb < DGRP; ++bb) acc[bb] += sk[bb][k] * wv;
    }
#pragma unroll
    for (int bb = 0; bb < DGRP; ++bb)
        h2[(size_t)(b0 + bb) * 1024 + n] = fmaxf(acc[bb], 0.f);
}

// -------- fc3: sigmoid, batch-grouped -------------------------------------------
__global__ __launch_bounds__(256) void fc3_kernel(const float* __restrict__ h2,
        const float* __restrict__ w, const float* __restrict__ bias,
        float* __restrict__ out) {
    int nc = blockIdx.x;                 // 0..3, chunks of 196
    int b0 = blockIdx.y * DGRP;
    int t = threadIdx.x;
    __shared__ float sk[DGRP][1024];
    for (int e = t; e < DGRP * 1024; e += 256) {
        int bb = e >> 10, k = e & 1023;
        sk[bb][k] = h2[(size_t)(b0 + bb) * 1024 + k];
    }
    __syncthreads();
    if (t >= 196) return;
    int n = nc * 196 + t;
    float acc[DGRP];
#pragma unroll
    for (int bb = 0; bb < DGRP; ++bb) acc[bb] = bias[n];
    for (int k = 0; k < 1024; ++k) {
        float wv = w[(size_t)k * 784 + n];
#pragma unroll
        for (int bb = 0; bb < DGRP; ++bb) acc[bb] += sk[bb][k] * wv;
    }
#pragma unroll
    for (int bb = 0; bb < DGRP; ++bb)
        out[1408 + (size_t)(b0 + bb) * 784 + n] = 1.f / (1.f + expf(-acc[bb]));
}

extern "C" void kernel_launch(void* const* d_in, const int* in_sizes, int n_in,
                              void* d_out, int out_size, void* d_ws, size_t ws_size,
                              hipStream_t stream) {
    const float* image = (const float*)d_in[0];
    const int*   target = (const int*)d_in[1];
    const float* w1  = (const float*)d_in[2];
    const float* b1  = (const float*)d_in[3];
    const float* w2  = (const float*)d_in[4];
    const float* b2  = (const float*)d_in[5];
    const float* Wm  = (const float*)d_in[6];
    const float* d1w = (const float*)d_in[7];
    const float* d1b = (const float*)d_in[8];
    const float* d2w = (const float*)d_in[9];
    const float* d2b = (const float*)d_in[10];
    const float* dow = (const float*)d_in[11];
    const float* dob = (const float*)d_in[12];
    float* out = (float*)d_out;
    float* ws  = (float*)d_ws;

    ushort* c1h  = (ushort*)(ws + WS_C1H);
    ushort* c1l  = (ushort*)(ws + WS_C1L);
    ushort* w2th = (ushort*)(ws + WS_W2TH);
    ushort* w2tl = (ushort*)(ws + WS_W2TL);

    int ksplit = 4;
    if (ws_size >= (size_t)(18415616 + 18 * 1179648) * 4) ksplit = 18;
    else if (ws_size >= (size_t)(18415616 + 12 * 1179648) * 4) ksplit = 12;
    else if (ws_size >= (size_t)(18415616 + 6 * 1179648) * 4) ksplit = 6;
    int nsteps = KSTEPS / ksplit / 2;
    int nwg = 144 * ksplit;

    float* s1acc = ws + WS_S12A;
    float* s2acc = ws + WS_S12A + 20480;

    convprep_kernel<<<3856, 256, 0, stream>>>(image, w1, b1, w2, c1h, c1l, w2th, w2tl);
    conv2_mfma_kernel<<<nwg, 256, 0, stream>>>(c1h, c1l, w2th, w2tl,
                                               ws + WS_CPART, nsteps, nwg);
    squash_pc_kernel<<<4608, 256, 0, stream>>>(ws + WS_CPART, b2, ws + WS_PC,
                                               ws + WS_S12A, ksplit);
    s1part_kernel<<<dim3(144, 8), 192, 0, stream>>>(Wm, ws + WS_PC, s1acc);
    c2s2_kernel<<<dim3(144, 8), 192, 0, stream>>>(Wm, ws + WS_PC, s1acc, s2acc);
    fc1_kernel<<<dim3(2, BSZ / DGRP), 256, 0, stream>>>(s2acc, target, d1w, d1b,
                                                        out, ws + WS_H1);
    fc2_kernel<<<dim3(4, BSZ / DGRP), 256, 0, stream>>>(ws + WS_H1, d2w, d2b, ws + WS_H2);
    fc3_kernel<<<dim3(4, BSZ / DGRP), 256, 0, stream>>>(ws + WS_H2, dow, dob, out);
}